// Round 1
// baseline (346.685 us; speedup 1.0000x reference)
//
#include <hip/hip_runtime.h>

// out[n,o] = sum_i x[n,i] * w[o,i] * att[n,i,o] + bias[o]
// N=256, I=1024, O=1024, all fp32. HBM-bound on the 1.07 GB attention tensor.

constexpr int Nn = 256;
constexpr int Ii = 1024;
constexpr int Oo = 1024;

constexpr int OCHUNK = 512;   // o-range per block
constexpr int TPB    = 256;   // threads per block -> 2 o per thread

__global__ __launch_bounds__(TPB)
void attn_linear_kernel(const float* __restrict__ x,
                        const float* __restrict__ att,
                        const float* __restrict__ w,
                        const float* __restrict__ bias,
                        float* __restrict__ out) {
    __shared__ float xs[Ii];

    const int n      = blockIdx.y;
    const int ochunk = blockIdx.x;
    const int tid    = threadIdx.x;

    // Stage x[n, :] (4 KB) into LDS: 256 threads x float4 = 1024 floats.
    {
        const float4* xrow = reinterpret_cast<const float4*>(x + (size_t)n * Ii);
        reinterpret_cast<float4*>(xs)[tid] = xrow[tid];
    }
    __syncthreads();

    const int o0 = ochunk * OCHUNK + tid * 2;

    const float* attp = att + ((size_t)n * Ii) * Oo + o0;  // + i*Oo per step
    const float* w0p  = w + (size_t)o0 * Ii;
    const float* w1p  = w + (size_t)(o0 + 1) * Ii;

    float acc0 = 0.f, acc1 = 0.f;

    #pragma unroll 2
    for (int i = 0; i < Ii; i += 4) {
        // weight: 16 B per lane, i-contiguous -> full 64B-line reuse, L1/L2 resident
        float4 w0 = *reinterpret_cast<const float4*>(w0p + i);
        float4 w1 = *reinterpret_cast<const float4*>(w1p + i);
        // x: uniform-address LDS broadcast
        float4 xv = *reinterpret_cast<const float4*>(&xs[i]);
        // attention: coalesced 8 B/lane streaming loads (the HBM-bound stream)
        float2 a0 = *reinterpret_cast<const float2*>(attp + (size_t)(i + 0) * Oo);
        float2 a1 = *reinterpret_cast<const float2*>(attp + (size_t)(i + 1) * Oo);
        float2 a2 = *reinterpret_cast<const float2*>(attp + (size_t)(i + 2) * Oo);
        float2 a3 = *reinterpret_cast<const float2*>(attp + (size_t)(i + 3) * Oo);

        acc0 = fmaf(xv.x * w0.x, a0.x, acc0);
        acc1 = fmaf(xv.x * w1.x, a0.y, acc1);
        acc0 = fmaf(xv.y * w0.y, a1.x, acc0);
        acc1 = fmaf(xv.y * w1.y, a1.y, acc1);
        acc0 = fmaf(xv.z * w0.z, a2.x, acc0);
        acc1 = fmaf(xv.z * w1.z, a2.y, acc1);
        acc0 = fmaf(xv.w * w0.w, a3.x, acc0);
        acc1 = fmaf(xv.w * w1.w, a3.y, acc1);
    }

    float2 result;
    result.x = acc0 + bias[o0];
    result.y = acc1 + bias[o0 + 1];
    *reinterpret_cast<float2*>(out + (size_t)n * Oo + o0) = result;
}

extern "C" void kernel_launch(void* const* d_in, const int* in_sizes, int n_in,
                              void* d_out, int out_size, void* d_ws, size_t ws_size,
                              hipStream_t stream) {
    const float* x    = (const float*)d_in[0];
    const float* att  = (const float*)d_in[1];
    const float* w    = (const float*)d_in[2];
    const float* bias = (const float*)d_in[3];
    float* out        = (float*)d_out;

    dim3 grid(Oo / OCHUNK, Nn);   // (2, 256)
    dim3 block(TPB);
    attn_linear_kernel<<<grid, block, 0, stream>>>(x, att, w, bias, out);
}